// Round 13
// baseline (869.751 us; speedup 1.0000x reference)
//
#include <hip/hip_runtime.h>
#include <math.h>

namespace {
constexpr int kB = 32;
constexpr int kS = 500;
constexpr int kH = 8;
}
// -ln(10000)/127
#define LKC (-0.07252236513366287)

typedef __attribute__((ext_vector_type(8))) short s16x8;
typedef __attribute__((ext_vector_type(4))) float f32x4;

__device__ __forceinline__ float gelu_f(float x){
  return 0.5f * x * (1.0f + erff(x * 0.7071067811865476f));
}
__device__ __forceinline__ float b2f(short s){
  union { unsigned u; float f; } x; x.u = ((unsigned)(unsigned short)s) << 16; return x.f;
}
__device__ __forceinline__ short f2b(float f){
  unsigned u = __float_as_uint(f);
  unsigned r = (u + 0x7fffu + ((u >> 16) & 1u)) >> 16;
  return (short)r;
}
// packed 2xfp32 -> 2xbf16 (RNE), D.lo = S0
__device__ __forceinline__ unsigned cvtpk(float lo, float hi){
  unsigned r;
  asm("v_cvt_pk_bf16_f32 %0, %1, %2" : "=v"(r) : "v"(lo), "v"(hi));
  return r;
}

// conv1 weight: (128,112) -> bf16 padded to (128,128)
__global__ __launch_bounds__(128) void conv1w_pad(const float* __restrict__ w, short* __restrict__ out){
  int n = blockIdx.x, k = threadIdx.x;
  out[n*128 + k] = (k < 112) ? f2b(w[n*112 + k]) : (short)0;
}

// ---------------- fused fp32 -> bf16 weight conversion (7 arrays, 1 launch) ----------------
__global__ __launch_bounds__(256) void f2b_all(const float* __restrict__ c2,
    const float* __restrict__ e1, const float* __restrict__ e2,
    const float* __restrict__ qk, const float* __restrict__ wo,
    const float* __restrict__ w1, const float* __restrict__ w2,
    short* __restrict__ WB){
  int blk = blockIdx.x, t = threadIdx.x;
  const float* src; short* dst; int idx;
  if(blk < 896){        src = c2; dst = WB + 16384;   idx = blk*256 + t; }
  else if(blk < 1664){  src = e1; dst = WB + 245760;  idx = (blk-896)*256 + t; }
  else if(blk < 1920){  src = e2; dst = WB + 442368;  idx = (blk-1664)*256 + t; }
  else if(blk < 6528){  src = qk; dst = WB + 507904;  idx = (blk-1920)*256 + t; }
  else if(blk < 8064){  src = wo; dst = WB + 1687552; idx = (blk-6528)*256 + t; }
  else if(blk < 14208){ src = w1; dst = WB + 2080768; idx = (blk-8064)*256 + t; }
  else {                src = w2; dst = WB + 3653632; idx = (blk-14208)*256 + t; }
  dst[idx] = f2b(src[idx]);
}

// ---------------- MFMA GEMM (256 thr, 128x128 tile): prologue/event GEMMs ----------------
template<int OUT, bool DOGELU>
__global__ __launch_bounds__(256) void gemm_mfma(const short* __restrict__ A,
    const short* __restrict__ W, const float* __restrict__ bias,
    void* __restrict__ Cv, int M, int N, int K){
  __shared__ __align__(16) short Al[128*64];
  __shared__ __align__(16) short Wl[128*64];
  const int t = threadIdx.x;
  const int wid = t >> 6, lane = t & 63;
  const int m0 = blockIdx.y * 128, n0 = blockIdx.x * 128;
  const int wr = (wid >> 1) * 64, wc = (wid & 1) * 64;
  const int frow = lane & 15, lg = lane >> 4;
  const int rA = t >> 3;
  const int sA = (t & 7) ^ (rA & 7);
  const short* Aq = A + (size_t)(m0 + rA) * K + sA * 8;
  const short* Wq = W + (size_t)(n0 + rA) * K + sA * 8;
  f32x4 acc[4][4] = {};
  for(int k0 = 0; k0 < K; k0 += 64){
    s16x8 av[4], wv[4];
    #pragma unroll
    for(int j = 0; j < 4; ++j){
      av[j] = *(const s16x8*)(Aq + k0 + (size_t)(32*j)*K);
      wv[j] = *(const s16x8*)(Wq + k0 + (size_t)(32*j)*K);
    }
    __syncthreads();
    #pragma unroll
    for(int j = 0; j < 4; ++j){
      *(s16x8*)&Al[t*8 + j*2048] = av[j];
      *(s16x8*)&Wl[t*8 + j*2048] = wv[j];
    }
    __syncthreads();
    #pragma unroll
    for(int kh = 0; kh < 2; ++kh){
      s16x8 a[4], b[4];
      #pragma unroll
      for(int mi = 0; mi < 4; ++mi){
        int r = wr + mi*16 + frow;
        a[mi] = *(const s16x8*)&Al[r*64 + (((kh*4 + lg) ^ (r & 7)) * 8)];
      }
      #pragma unroll
      for(int ni = 0; ni < 4; ++ni){
        int r = wc + ni*16 + frow;
        b[ni] = *(const s16x8*)&Wl[r*64 + (((kh*4 + lg) ^ (r & 7)) * 8)];
      }
      #pragma unroll
      for(int mi = 0; mi < 4; ++mi)
        #pragma unroll
        for(int ni = 0; ni < 4; ++ni)
          acc[mi][ni] = __builtin_amdgcn_mfma_f32_16x16x32_bf16(a[mi], b[ni], acc[mi][ni], 0, 0, 0);
    }
  }
  #pragma unroll
  for(int mi = 0; mi < 4; ++mi){
    #pragma unroll
    for(int ni = 0; ni < 4; ++ni){
      const int col = n0 + wc + ni*16 + (lane & 15);
      const float bv = bias[col];
      #pragma unroll
      for(int r = 0; r < 4; ++r){
        const int row = m0 + wr + mi*16 + (lane >> 4)*4 + r;
        float v = acc[mi][ni][r] + bv;
        if(DOGELU) v = gelu_f(v);
        if(OUT == 0) ((float*)Cv)[(size_t)row*N + col] = v;
        else if(OUT == 1) ((float*)Cv)[(size_t)row*N + col] += v;
        else ((short*)Cv)[(size_t)row*N + col] = f2b(v);
      }
    }
  }
}

// ---------------- gemm512: 128Mx256N tile, 512 threads (8 waves of 64x64), BK=64 ----------------
template<bool DOGELU>
__global__ __launch_bounds__(512) void gemm512(const short* __restrict__ A,
    const short* __restrict__ W, const float* __restrict__ bias,
    short* __restrict__ C, int M, int N, int K){
  __shared__ __align__(16) short Al[128*64];
  __shared__ __align__(16) short Wl[256*64];
  const int t = threadIdx.x;
  const int wid = t >> 6, lane = t & 63;
  const int m0 = blockIdx.y * 128, n0 = blockIdx.x * 256;
  const int wm = wid >> 2, wn = wid & 3;
  const int frow = lane & 15, lg = lane >> 4;
  const int rA = t >> 3;
  const int sA = (t & 7) ^ (rA & 7);
  const short* Aq = A + (size_t)(m0 + rA) * K + sA * 8;
  const short* Wq = W + (size_t)(n0 + rA) * K + sA * 8;
  f32x4 acc[4][4] = {};
  for(int k0 = 0; k0 < K; k0 += 64){
    s16x8 av[2], wv[4];
    av[0] = *(const s16x8*)(Aq + k0);
    av[1] = *(const s16x8*)(Aq + k0 + (size_t)64*K);
    #pragma unroll
    for(int j = 0; j < 4; ++j)
      wv[j] = *(const s16x8*)(Wq + k0 + (size_t)(64*j)*K);
    __syncthreads();
    *(s16x8*)&Al[t*8] = av[0];
    *(s16x8*)&Al[t*8 + 4096] = av[1];
    #pragma unroll
    for(int j = 0; j < 4; ++j)
      *(s16x8*)&Wl[t*8 + j*4096] = wv[j];
    __syncthreads();
    #pragma unroll
    for(int kh = 0; kh < 2; ++kh){
      s16x8 a[4], b[4];
      #pragma unroll
      for(int mi = 0; mi < 4; ++mi){
        int r = wm*64 + mi*16 + frow;
        a[mi] = *(const s16x8*)&Al[r*64 + (((kh*4 + lg) ^ (r & 7)) * 8)];
      }
      #pragma unroll
      for(int ni = 0; ni < 4; ++ni){
        int r = wn*64 + ni*16 + frow;
        b[ni] = *(const s16x8*)&Wl[r*64 + (((kh*4 + lg) ^ (r & 7)) * 8)];
      }
      #pragma unroll
      for(int mi = 0; mi < 4; ++mi)
        #pragma unroll
        for(int ni = 0; ni < 4; ++ni)
          acc[mi][ni] = __builtin_amdgcn_mfma_f32_16x16x32_bf16(a[mi], b[ni], acc[mi][ni], 0, 0, 0);
    }
  }
  #pragma unroll
  for(int mi = 0; mi < 4; ++mi){
    #pragma unroll
    for(int ni = 0; ni < 4; ++ni){
      const int col = n0 + wn*64 + ni*16 + (lane & 15);
      const float bv = bias[col];
      #pragma unroll
      for(int r = 0; r < 4; ++r){
        const int row = m0 + wm*64 + mi*16 + (lane >> 4)*4 + r;
        float v = acc[mi][ni][r] + bv;
        if(DOGELU) v = gelu_f(v);
        C[(size_t)row*N + col] = f2b(v);
      }
    }
  }
}

// ---------------- gemm_ln: 64Mx256N, N==256: X += A@W^T+bias; optional row-LN -> XNB ----------------
template<bool DOLN>
__global__ __launch_bounds__(512) void gemm_ln(const short* __restrict__ A,
    const short* __restrict__ W, const float* __restrict__ bias,
    float* __restrict__ X, const float* __restrict__ lg_, const float* __restrict__ lb_,
    short* __restrict__ XNB, int M, int K){
  __shared__ __align__(16) short Al[64*64];
  __shared__ __align__(16) short Wl[256*64];
  __shared__ float sbuf[64][4];
  const int t = threadIdx.x;
  const int wid = t >> 6, lane = t & 63;
  const int m0 = blockIdx.y * 64;
  const int wm = wid >> 2, wn = wid & 3;
  const int frow = lane & 15, lg = lane >> 4;
  const int lq = lane & 15;
  const int rA = t >> 3;
  const int sA = (t & 7) ^ (rA & 7);
  const short* Aq = A + (size_t)(m0 + rA) * K + sA * 8;
  const short* Wq = W + (size_t)rA * K + sA * 8;
  f32x4 acc[2][4] = {};
  for(int k0 = 0; k0 < K; k0 += 64){
    s16x8 av = *(const s16x8*)(Aq + k0);
    s16x8 wv[4];
    #pragma unroll
    for(int j = 0; j < 4; ++j)
      wv[j] = *(const s16x8*)(Wq + k0 + (size_t)(64*j)*K);
    __syncthreads();
    *(s16x8*)&Al[t*8] = av;
    #pragma unroll
    for(int j = 0; j < 4; ++j)
      *(s16x8*)&Wl[t*8 + j*4096] = wv[j];
    __syncthreads();
    #pragma unroll
    for(int kh = 0; kh < 2; ++kh){
      s16x8 a[2], b[4];
      #pragma unroll
      for(int mi = 0; mi < 2; ++mi){
        int r = wm*32 + mi*16 + frow;
        a[mi] = *(const s16x8*)&Al[r*64 + (((kh*4 + lg) ^ (r & 7)) * 8)];
      }
      #pragma unroll
      for(int ni = 0; ni < 4; ++ni){
        int r = wn*64 + ni*16 + frow;
        b[ni] = *(const s16x8*)&Wl[r*64 + (((kh*4 + lg) ^ (r & 7)) * 8)];
      }
      #pragma unroll
      for(int mi = 0; mi < 2; ++mi)
        #pragma unroll
        for(int ni = 0; ni < 4; ++ni)
          acc[mi][ni] = __builtin_amdgcn_mfma_f32_16x16x32_bf16(a[mi], b[ni], acc[mi][ni], 0, 0, 0);
    }
  }
  // v = acc + bias + residual
  float v[2][4][4];
  #pragma unroll
  for(int mi = 0; mi < 2; ++mi)
    #pragma unroll
    for(int ni = 0; ni < 4; ++ni){
      const int col = wn*64 + ni*16 + lq;
      const float bv = bias[col];
      #pragma unroll
      for(int r = 0; r < 4; ++r){
        const int row = m0 + wm*32 + mi*16 + lg*4 + r;
        v[mi][ni][r] = acc[mi][ni][r] + bv + X[(size_t)row*256 + col];
      }
    }
  __syncthreads();
  float vmean[2][4], vrstd[2][4];
  if(DOLN){
    #pragma unroll
    for(int mi = 0; mi < 2; ++mi)
      #pragma unroll
      for(int r = 0; r < 4; ++r){
        float s = v[mi][0][r] + v[mi][1][r] + v[mi][2][r] + v[mi][3][r];
        s += __shfl_xor(s, 1); s += __shfl_xor(s, 2);
        s += __shfl_xor(s, 4); s += __shfl_xor(s, 8);
        if(lq == 0) sbuf[wm*32 + mi*16 + lg*4 + r][wn] = s;
      }
    __syncthreads();
    #pragma unroll
    for(int mi = 0; mi < 2; ++mi)
      #pragma unroll
      for(int r = 0; r < 4; ++r){
        int rl = wm*32 + mi*16 + lg*4 + r;
        vmean[mi][r] = (sbuf[rl][0] + sbuf[rl][1] + sbuf[rl][2] + sbuf[rl][3]) * (1.f/256.f);
      }
    __syncthreads();
    #pragma unroll
    for(int mi = 0; mi < 2; ++mi)
      #pragma unroll
      for(int r = 0; r < 4; ++r){
        float q = 0.f;
        #pragma unroll
        for(int ni = 0; ni < 4; ++ni){ float d = v[mi][ni][r] - vmean[mi][r]; q += d*d; }
        q += __shfl_xor(q, 1); q += __shfl_xor(q, 2);
        q += __shfl_xor(q, 4); q += __shfl_xor(q, 8);
        if(lq == 0) sbuf[wm*32 + mi*16 + lg*4 + r][wn] = q;
      }
    __syncthreads();
    #pragma unroll
    for(int mi = 0; mi < 2; ++mi)
      #pragma unroll
      for(int r = 0; r < 4; ++r){
        int rl = wm*32 + mi*16 + lg*4 + r;
        float Q = sbuf[rl][0] + sbuf[rl][1] + sbuf[rl][2] + sbuf[rl][3];
        vrstd[mi][r] = 1.f / sqrtf(Q * (1.f/256.f) + 1e-5f);
      }
  }
  #pragma unroll
  for(int mi = 0; mi < 2; ++mi)
    #pragma unroll
    for(int ni = 0; ni < 4; ++ni){
      const int col = wn*64 + ni*16 + lq;
      float gg = 0.f, bb = 0.f;
      if(DOLN){ gg = lg_[col]; bb = lb_[col]; }
      #pragma unroll
      for(int r = 0; r < 4; ++r){
        const int row = m0 + wm*32 + mi*16 + lg*4 + r;
        float val = v[mi][ni][r];
        X[(size_t)row*256 + col] = val;
        if(DOLN)
          XNB[(size_t)row*256 + col] = f2b((val - vmean[mi][r]) * vrstd[mi][r] * gg + bb);
      }
    }
}

// ---------------- gemm_fused: [GEMM1(N=256,K=K1) + resid + LN -> LDS] then GEMM2(N2,K=256) ----------------
// Phase1: X += A1@W1^T + b1; LN(row) -> XNl (LDS, stride 264).
// Phase2: C2 = [GELU](XNl @ W2^T + b2), bf16. grid = M/64 blocks x 512 threads.
template<bool DOGELU2>
__global__ __launch_bounds__(512) void gemm_fused(const short* __restrict__ A1,
    const short* __restrict__ W1, const float* __restrict__ b1,
    float* __restrict__ X, const float* __restrict__ lng, const float* __restrict__ lnb,
    const short* __restrict__ W2, const float* __restrict__ b2,
    short* __restrict__ C2, int M, int K1, int N2){
  __shared__ __align__(16) short Al[64*64];
  __shared__ __align__(16) short Wl[256*64];
  __shared__ __align__(16) short XNl[64*264];
  __shared__ float sbuf[64][4];
  const int t = threadIdx.x;
  const int wid = t >> 6, lane = t & 63;
  const int m0 = blockIdx.x * 64;
  const int wm = wid >> 2, wn = wid & 3;
  const int frow = lane & 15, lg = lane >> 4;
  const int lq = lane & 15;
  const int rA = t >> 3;
  const int sA = (t & 7) ^ (rA & 7);
  const short* Aq = A1 + (size_t)(m0 + rA) * K1 + sA * 8;
  const short* Wq = W1 + (size_t)rA * K1 + sA * 8;
  f32x4 acc[2][4] = {};
  for(int k0 = 0; k0 < K1; k0 += 64){
    s16x8 av = *(const s16x8*)(Aq + k0);
    s16x8 wv[4];
    #pragma unroll
    for(int j = 0; j < 4; ++j)
      wv[j] = *(const s16x8*)(Wq + k0 + (size_t)(64*j)*K1);
    __syncthreads();
    *(s16x8*)&Al[t*8] = av;
    #pragma unroll
    for(int j = 0; j < 4; ++j)
      *(s16x8*)&Wl[t*8 + j*4096] = wv[j];
    __syncthreads();
    #pragma unroll
    for(int kh = 0; kh < 2; ++kh){
      s16x8 a[2], b[4];
      #pragma unroll
      for(int mi = 0; mi < 2; ++mi){
        int r = wm*32 + mi*16 + frow;
        a[mi] = *(const s16x8*)&Al[r*64 + (((kh*4 + lg) ^ (r & 7)) * 8)];
      }
      #pragma unroll
      for(int ni = 0; ni < 4; ++ni){
        int r = wn*64 + ni*16 + frow;
        b[ni] = *(const s16x8*)&Wl[r*64 + (((kh*4 + lg) ^ (r & 7)) * 8)];
      }
      #pragma unroll
      for(int mi = 0; mi < 2; ++mi)
        #pragma unroll
        for(int ni = 0; ni < 4; ++ni)
          acc[mi][ni] = __builtin_amdgcn_mfma_f32_16x16x32_bf16(a[mi], b[ni], acc[mi][ni], 0, 0, 0);
    }
  }
  // ---- phase1 epilogue: v = acc + bias + residual; LN; write X + XNl ----
  float v[2][4][4];
  #pragma unroll
  for(int mi = 0; mi < 2; ++mi)
    #pragma unroll
    for(int ni = 0; ni < 4; ++ni){
      const int col = wn*64 + ni*16 + lq;
      const float bv = b1[col];
      #pragma unroll
      for(int r = 0; r < 4; ++r){
        const int row = m0 + wm*32 + mi*16 + lg*4 + r;
        v[mi][ni][r] = acc[mi][ni][r] + bv + X[(size_t)row*256 + col];
      }
    }
  __syncthreads();
  float vmean[2][4], vrstd[2][4];
  #pragma unroll
  for(int mi = 0; mi < 2; ++mi)
    #pragma unroll
    for(int r = 0; r < 4; ++r){
      float s = v[mi][0][r] + v[mi][1][r] + v[mi][2][r] + v[mi][3][r];
      s += __shfl_xor(s, 1); s += __shfl_xor(s, 2);
      s += __shfl_xor(s, 4); s += __shfl_xor(s, 8);
      if(lq == 0) sbuf[wm*32 + mi*16 + lg*4 + r][wn] = s;
    }
  __syncthreads();
  #pragma unroll
  for(int mi = 0; mi < 2; ++mi)
    #pragma unroll
    for(int r = 0; r < 4; ++r){
      int rl = wm*32 + mi*16 + lg*4 + r;
      vmean[mi][r] = (sbuf[rl][0] + sbuf[rl][1] + sbuf[rl][2] + sbuf[rl][3]) * (1.f/256.f);
    }
  __syncthreads();
  #pragma unroll
  for(int mi = 0; mi < 2; ++mi)
    #pragma unroll
    for(int r = 0; r < 4; ++r){
      float q = 0.f;
      #pragma unroll
      for(int ni = 0; ni < 4; ++ni){ float d = v[mi][ni][r] - vmean[mi][r]; q += d*d; }
      q += __shfl_xor(q, 1); q += __shfl_xor(q, 2);
      q += __shfl_xor(q, 4); q += __shfl_xor(q, 8);
      if(lq == 0) sbuf[wm*32 + mi*16 + lg*4 + r][wn] = q;
    }
  __syncthreads();
  #pragma unroll
  for(int mi = 0; mi < 2; ++mi)
    #pragma unroll
    for(int r = 0; r < 4; ++r){
      int rl = wm*32 + mi*16 + lg*4 + r;
      float Q = sbuf[rl][0] + sbuf[rl][1] + sbuf[rl][2] + sbuf[rl][3];
      vrstd[mi][r] = 1.f / sqrtf(Q * (1.f/256.f) + 1e-5f);
    }
  #pragma unroll
  for(int mi = 0; mi < 2; ++mi)
    #pragma unroll
    for(int ni = 0; ni < 4; ++ni){
      const int col = wn*64 + ni*16 + lq;
      const float gg = lng[col], bb = lnb[col];
      #pragma unroll
      for(int r = 0; r < 4; ++r){
        const int rowl = wm*32 + mi*16 + lg*4 + r;
        float val = v[mi][ni][r];
        X[(size_t)(m0 + rowl)*256 + col] = val;
        XNl[rowl*264 + col] = f2b((val - vmean[mi][r]) * vrstd[mi][r] * gg + bb);
      }
    }
  // ---- phase2: C2 = act(XNl @ W2^T + b2), N2 cols in chunks of 256 ----
  for(int nc = 0; nc < N2; nc += 256){
    f32x4 acc2[2][4] = {};
    const short* Wq2 = W2 + (size_t)(nc + rA) * 256 + sA * 8;
    #pragma unroll
    for(int k0 = 0; k0 < 256; k0 += 64){
      s16x8 wv[4];
      #pragma unroll
      for(int j = 0; j < 4; ++j)
        wv[j] = *(const s16x8*)(Wq2 + k0 + (size_t)(64*j)*256);
      __syncthreads();   // first one also fences XNl writes
      #pragma unroll
      for(int j = 0; j < 4; ++j)
        *(s16x8*)&Wl[t*8 + j*4096] = wv[j];
      __syncthreads();
      #pragma unroll
      for(int kh = 0; kh < 2; ++kh){
        s16x8 a[2], b[4];
        #pragma unroll
        for(int mi = 0; mi < 2; ++mi)
          a[mi] = *(const s16x8*)&XNl[(wm*32 + mi*16 + frow)*264 + k0 + kh*32 + lg*8];
        #pragma unroll
        for(int ni = 0; ni < 4; ++ni){
          int r = wn*64 + ni*16 + frow;
          b[ni] = *(const s16x8*)&Wl[r*64 + (((kh*4 + lg) ^ (r & 7)) * 8)];
        }
        #pragma unroll
        for(int mi = 0; mi < 2; ++mi)
          #pragma unroll
          for(int ni = 0; ni < 4; ++ni)
            acc2[mi][ni] = __builtin_amdgcn_mfma_f32_16x16x32_bf16(a[mi], b[ni], acc2[mi][ni], 0, 0, 0);
      }
    }
    #pragma unroll
    for(int mi = 0; mi < 2; ++mi)
      #pragma unroll
      for(int ni = 0; ni < 4; ++ni){
        const int col = nc + wn*64 + ni*16 + lq;
        const float bv = b2[col];
        #pragma unroll
        for(int r = 0; r < 4; ++r){
          const int row = m0 + wm*32 + mi*16 + lg*4 + r;
          float vv = acc2[mi][ni][r] + bv;
          if(DOGELU2) vv = gelu_f(vv);
          C2[(size_t)row*N2 + col] = f2b(vv);
        }
      }
  }
}

// ---------------- mel compress: (B,80,2000) -> (B,16,2000) ----------------
__global__ __launch_bounds__(256) void mel_kernel(const float* __restrict__ mel,
    const float* __restrict__ W, const float* __restrict__ bias, float* __restrict__ xm){
  __shared__ float Ws[16][80];
  __shared__ float bs[16];
  const int t = threadIdx.x;
  for(int i = t; i < 16*80; i += 256) Ws[i/80][i%80] = W[i];
  if(t < 16) bs[t] = bias[t];
  __syncthreads();
  int blk = blockIdx.x;
  int b = blk >> 3;
  int tc = (blk & 7) * 256 + t;
  if(tc >= 2000) return;
  float acc[16];
  #pragma unroll
  for(int o = 0; o < 16; ++o) acc[o] = bs[o];
  for(int c = 0; c < 80; ++c){
    float v = mel[((size_t)b*80 + c)*2000 + tc];
    #pragma unroll
    for(int o = 0; o < 16; ++o) acc[o] += v * Ws[o][c];
  }
  #pragma unroll
  for(int o = 0; o < 16; ++o) xm[((size_t)b*16 + o)*2000 + tc] = acc[o];
}

// ---------------- im2col conv1 -> bf16, K padded to 128 ----------------
__global__ __launch_bounds__(256) void im2col1b(const float* __restrict__ xm, short* __restrict__ A){
  size_t idx = (size_t)blockIdx.x * 256 + threadIdx.x; // 32000*128
  int col = idx & 127;
  size_t row = idx >> 7;
  int t1 = row % 1000, b = row / 1000;
  float v = 0.f;
  if(col < 112){
    int i = col / 7, k = col % 7;
    int src = 2*t1 + k - 3;
    if(src >= 0 && src < 2000) v = xm[((size_t)b*16 + i)*2000 + src];
  }
  A[idx] = f2b(v);
}

// ---------------- GroupNorm(1) stats: two-stage ----------------
__global__ __launch_bounds__(256) void gn_part(const float* __restrict__ h1, double* __restrict__ part){
  int blk = blockIdx.x;  // 256 = 32 b x 8 segs
  const float* p = h1 + (size_t)blk * 16000;
  int t = threadIdx.x;
  double s = 0, q = 0;
  for(int i = t; i < 16000; i += 256){ double v = p[i]; s += v; q += v*v; }
  __shared__ double rs[256], rq[256];
  rs[t] = s; rq[t] = q; __syncthreads();
  for(int s2 = 128; s2 > 0; s2 >>= 1){
    if(t < s2){ rs[t] += rs[t+s2]; rq[t] += rq[t+s2]; }
    __syncthreads();
  }
  if(t == 0){ part[blk*2] = rs[0]; part[blk*2+1] = rq[0]; }
}
__global__ __launch_bounds__(256) void gn_final(const double* __restrict__ part, float* __restrict__ stats){
  int t = threadIdx.x;     // 256 = 32 b x 8
  int b = t >> 3;
  double s = part[t*2], q = part[t*2+1];
  s += __shfl_xor(s, 1); q += __shfl_xor(q, 1);
  s += __shfl_xor(s, 2); q += __shfl_xor(q, 2);
  s += __shfl_xor(s, 4); q += __shfl_xor(q, 4);
  if((t & 7) == 0){
    double mean = s / 128000.0;
    double var  = q / 128000.0 - mean*mean;
    stats[b*2]   = (float)mean;
    stats[b*2+1] = (float)(1.0 / sqrt(var + 1e-5));
  }
}

// ---------------- im2col conv2 (fused GroupNorm) -> bf16 ----------------
__global__ __launch_bounds__(256) void im2col2b(const float* __restrict__ h1,
    const float* __restrict__ stats, const float* __restrict__ gg,
    const float* __restrict__ gb, short* __restrict__ A){
  size_t idx = (size_t)blockIdx.x * 256 + threadIdx.x; // 16000*896
  int col = idx % 896;
  size_t row = idx / 896;
  int t2 = row % 500, b = row / 500;
  int i = col / 7, k = col % 7;
  int src = 2*t2 + k - 3;
  float v = 0.f;
  if(src >= 0 && src < 1000){
    float raw = h1[((size_t)b*1000 + src)*128 + i];
    v = (raw - stats[b*2]) * stats[b*2+1] * gg[i] + gb[i];
  }
  A[idx] = f2b(v);
}

// ---------------- post-conv: LN(D) + sinpos + star table -> X (fp32) ----------------
__global__ __launch_bounds__(256) void postconv(const float* __restrict__ xp,
    const float* __restrict__ cg, const float* __restrict__ cb,
    const float* __restrict__ star, const float* __restrict__ stab,
    float* __restrict__ x){
  int row = blockIdx.x, t = threadIdx.x;
  int s = row % 500, b = row / 500;
  __shared__ float red[256];
  float v = xp[(size_t)row*256 + t];
  red[t] = v; __syncthreads();
  for(int s2 = 128; s2 > 0; s2 >>= 1){ if(t < s2) red[t] += red[t+s2]; __syncthreads(); }
  float mean = red[0] / 256.f; __syncthreads();
  float d = v - mean;
  red[t] = d*d; __syncthreads();
  for(int s2 = 128; s2 > 0; s2 >>= 1){ if(t < s2) red[t] += red[t+s2]; __syncthreads(); }
  float rstd = 1.f / sqrtf(red[0]/256.f + 1e-5f);
  int j = t & 127;
  double f = exp((double)j * LKC);
  double a = (double)s * f;
  float pe = (float)(t < 128 ? sin(a) : cos(a));
  int bucket = (int)(star[b] * 2.0f);
  bucket = bucket < 0 ? 0 : (bucket > 19 ? 19 : bucket);
  x[(size_t)row*256 + t] = d*rstd*cg[t] + cb[t] + pe + stab[bucket*256 + t];
}

// ---------------- event features -> combined bf16 (B*NEV, 768) ----------------
__global__ __launch_bounds__(256) void event_feat(const int* __restrict__ events, short* __restrict__ comb){
  int blk = blockIdx.x;           // 8192
  int e = blk & 255, b = blk >> 8;
  const int* ev = events + b*256;
  int t = threadIdx.x;
  auto gof = [&](int i){ int j = i < 1 ? 1 : i; int d = ev[j] - ev[j-1]; return d < 1 ? 1 : d; };
  int gi = gof(e);
  double rb = 1.0, ra = 1.0;
  if(e != 0){
    rb = (double)gi / (double)gof(e-1);
    rb = rb < 0.1 ? 0.1 : (rb > 10.0 ? 10.0 : rb);
  }
  if(e != 255){
    ra = (double)gof(e+1) / (double)gi;
    ra = ra < 0.1 ? 0.1 : (ra > 10.0 ? 10.0 : ra);
  }
  int rbi = (int)(rb * 50.0);
  int rai = (int)(ra * 50.0);
  int gap = 5 * gi;
  int j = t & 127;
  double f = exp((double)j * LKC);
  double a0 = (double)rbi * f, a1 = (double)rai * f, a2 = (double)gap * f;
  size_t base = (size_t)blk * 768;
  comb[base + t]       = f2b((float)(t < 128 ? sin(a0) : cos(a0)));
  comb[base + 256 + t] = f2b((float)(t < 128 ? sin(a1) : cos(a1)));
  comb[base + 512 + t] = f2b((float)(t < 128 ? sin(a2) : cos(a2)));
}

// ---------------- scatter-add events into X ----------------
__global__ __launch_bounds__(256) void ev_scatter(const float* __restrict__ evout,
    const int* __restrict__ events, const unsigned char* __restrict__ mask,
    float* __restrict__ x){
  int blk = blockIdx.x; // 8192
  int e = blk & 255, b = blk >> 8;
  if(mask[b*256 + e]) return;
  int tp = events[b*256 + e] >> 2;
  tp = tp < 0 ? 0 : (tp > 499 ? 499 : tp);
  int t = threadIdx.x;
  atomicAdd(&x[((size_t)b*500 + tp)*256 + t], evout[(size_t)blk*256 + t]);
}

// ---------------- LayerNorm rows of 256 -> bf16 (wave-shuffle reduce) ----------------
__global__ __launch_bounds__(256) void ln_rows(const float* __restrict__ x,
    const float* __restrict__ g, const float* __restrict__ b, short* __restrict__ out){
  int row = blockIdx.x, t = threadIdx.x;
  int wid = t >> 6, lane = t & 63;
  __shared__ float sm[8];
  float v = x[(size_t)row*256 + t];
  float s = v;
  #pragma unroll
  for(int o = 1; o < 64; o <<= 1) s += __shfl_xor(s, o);
  if(lane == 0) sm[wid] = s;
  __syncthreads();
  float mean = (sm[0] + sm[1] + sm[2] + sm[3]) * (1.f/256.f);
  float d = v - mean;
  float q = d*d;
  #pragma unroll
  for(int o = 1; o < 64; o <<= 1) q += __shfl_xor(q, o);
  if(lane == 0) sm[4 + wid] = q;
  __syncthreads();
  float rstd = 1.f / sqrtf((sm[4] + sm[5] + sm[6] + sm[7]) * (1.f/256.f) + 1e-5f);
  out[(size_t)row*256 + t] = f2b(d*rstd*g[t] + b[t]);
}

// ---------------- MFMA flash attention: split-q, two-pass K halves ----------------
__global__ __launch_bounds__(512) void attn_mfma(const short* __restrict__ qkv,
    short* __restrict__ o){
  __shared__ __align__(16) short Kl[256*40];      // 20 KB
  __shared__ __align__(16) short Vt[32*264];      // 16.5 KB
  __shared__ __align__(16) short Pl[8][2][640];   // 20 KB (double-buffered per wave)
  const int i = blockIdx.x;
  const int b = (i & 7)*4 + ((i >> 3) & 3);       // same b -> same XCD
  const int qh = (i >> 5) & 1;                    // q-half
  const int h = (i >> 6) & 7;
  const int t = threadIdx.x;
  const int wid = t >> 6, lane = t & 63;
  const int lq = lane & 15, lg = lane >> 4;
  const short* base = qkv + (size_t)b * kS * 768;
  const float c2 = 0.17677669529663687f * 1.4426950408889634f;
  s16x8 qf[2];
  #pragma unroll
  for(int qi = 0; qi < 2; ++qi){
    int qrow = (qh*16 + wid*2 + qi)*16 + lq;
    if(qrow > kS-1) qrow = kS-1;
    qf[qi] = *(const s16x8*)(base + (size_t)qrow*768 + h*32 + lg*8);
  }
  float lsum[2] = {0.f, 0.f};
  f32x4 oa0[2] = {}, oa1[2] = {};
  for(int khalf = 0; khalf < 2; ++khalf){
    const int k0base = khalf * 256;
    if(khalf) __syncthreads();
    {
      const int c = t & 3;
      for(int idx = t; idx < 1024; idx += 512){
        int row = idx >> 2;
        int grow = k0base + row;
        s16x8 kv = {0,0,0,0,0,0,0,0};
        unsigned vu0 = 0, vu1 = 0, vu2 = 0, vu3 = 0;
        if(grow < kS){
          const short* rp = base + (size_t)grow*768 + 256 + h*32 + c*8;
          kv = *(const s16x8*)rp;
          uint4 vv = *(const uint4*)(rp + 256);
          vu0 = vv.x; vu1 = vv.y; vu2 = vv.z; vu3 = vv.w;
        }
        *(s16x8*)&Kl[row*40 + c*8] = kv;
        unsigned b0 = (c & 2) ? vu2 : vu0, b1 = (c & 2) ? vu3 : vu1;
        unsigned b2 = (c & 2) ? vu0 : vu2, b3 = (c & 2) ? vu1 : vu3;
        unsigned r0 = (c & 1) ? b1 : b0, r1 = (c & 1) ? b2 : b1;
        unsigned r2 = (c & 1) ? b3 : b2, r3 = (c & 1) ? b0 : b3;
        #pragma unroll
        for(int j0 = 0; j0 < 8; ++j0){
          unsigned w = (j0 >> 1) == 0 ? r0 : (j0 >> 1) == 1 ? r1 : (j0 >> 1) == 2 ? r2 : r3;
          short val = (short)((j0 & 1) ? (w >> 16) : (w & 0xffff));
          int d = c*8 + ((j0 + 2*c) & 7);
          Vt[d*264 + row] = val;
        }
      }
    }
    __syncthreads();
    #pragma unroll
    for(int qi = 0; qi < 2; ++qi){
      f32x4 sc[16];
      __builtin_amdgcn_s_setprio(1);
      #pragma unroll
      for(int kt = 0; kt < 16; ++kt){
        s16x8 kf = *(const s16x8*)&Kl[(kt*16 + lq)*40 + lg*8];
        f32x4 z = {0.f,0.f,0.f,0.f};
        sc[kt] = __builtin_amdgcn_mfma_f32_16x16x32_bf16(kf, qf[qi], z, 0, 0, 0);
      }
      __builtin_amdgcn_s_setprio(0);
      if(khalf == 1 && lg >= 1){ sc[15][0] = -1e30f; sc[15][1] = -1e30f; sc[15][2] = -1e30f; sc[15][3] = -1e30f; }
      float l0 = 0.f, l1 = 0.f, l2 = 0.f, l3 = 0.f;
      #pragma unroll
      for(int kt = 0; kt < 16; ++kt){
        float p0 = exp2f(sc[kt][0] * c2);
        float p1 = exp2f(sc[kt][1] * c2);
        float p2 = exp2f(sc[kt][2] * c2);
        float p3 = exp2f(sc[kt][3] * c2);
        sc[kt][0] = p0; sc[kt][1] = p1; sc[kt][2] = p2; sc[kt][3] = p3;
        l0 += p0; l1 += p1; l2 += p2; l3 += p3;
      }
      lsum[qi] += (l0 + l1) + (l2 + l3);
      #pragma unroll
      for(int kt2 = 0; kt2 < 8; ++kt2){
        short* pw = &Pl[wid][kt2 & 1][0];
        f32x4 p0 = sc[kt2*2], p1 = sc[kt2*2+1];
        uint2 pk0, pk1;
        pk0.x = cvtpk(p0[0], p0[1]); pk0.y = cvtpk(p0[2], p0[3]);
        pk1.x = cvtpk(p1[0], p1[1]); pk1.y = cvtpk(p1[2], p1[3]);
        *(uint2*)&pw[lq*40 + lg*4] = pk0;
        *(uint2*)&pw[lq*40 + 16 + lg*4] = pk1;
        s16x8 pf = *(const s16x8*)&pw[lq*40 + lg*8];
        s16x8 v0 = *(const s16x8*)&Vt[lq*264 + kt2*32 + lg*8];
        s16x8 v1 = *(const s16x8*)&Vt[(16+lq)*264 + kt2*32 + lg*8];
        __builtin_amdgcn_s_setprio(1);
        oa0[qi] = __builtin_amdgcn_mfma_f32_16x16x32_bf16(v0, pf, oa0[qi], 0, 0, 0);
        oa1[qi] = __builtin_amdgcn_mfma_f32_16x16x32_bf16(v1, pf, oa1[qi], 0, 0, 0);
        __builtin_amdgcn_s_setprio(0);
      }
    }
  }
  #pragma unroll
  for(int qi = 0; qi < 2; ++qi){
    float l = lsum[qi];
    l += __shfl_xor(l, 16, 64);
    l += __shfl_xor(l, 32, 64);
    float inv = 1.f / l;
    int qw = (qh*16 + wid*2 + qi)*16 + lq;
    if(qw < kS){
      short* op = o + ((size_t)(b*kS + qw))*256 + h*32;
      uint2 w0, w1;
      w0.x = cvtpk(oa0[qi][0]*inv, oa0[qi][1]*inv); w0.y = cvtpk(oa0[qi][2]*inv, oa0[qi][3]*inv);
      w1.x = cvtpk(oa1[qi][0]*inv, oa1[qi][1]*inv); w1.y = cvtpk(oa1[qi][2]*inv, oa1[qi][3]*inv);
      *(uint2*)&op[lg*4] = w0;
      *(uint2*)&op[16 + lg*4] = w1;
    }
  }
}

// ---------------- attention pooling + LN + head ----------------
__global__ __launch_bounds__(256) void pool_head(const float* __restrict__ x,
    const float* __restrict__ pq, const float* __restrict__ og, const float* __restrict__ ob,
    const float* __restrict__ ohW, const float* __restrict__ ohb, float* __restrict__ out){
  int b = blockIdx.x, t = threadIdx.x;
  __shared__ float lg[500];
  __shared__ float red[256];
  const float* xb = x + (size_t)b * 500 * 256;
  for(int s = t; s < 500; s += 256){
    const float* xr = xb + (size_t)s * 256;
    float d = 0.f;
    for(int c = 0; c < 256; ++c) d += xr[c] * pq[c];
    lg[s] = d * 0.0625f;
  }
  __syncthreads();
  float m = -1e30f;
  for(int s = t; s < 500; s += 256) m = fmaxf(m, lg[s]);
  red[t] = m; __syncthreads();
  for(int s2 = 128; s2 > 0; s2 >>= 1){ if(t < s2) red[t] = fmaxf(red[t], red[t+s2]); __syncthreads(); }
  m = red[0]; __syncthreads();
  float ps = 0.f;
  for(int s = t; s < 500; s += 256){ float e = expf(lg[s] - m); lg[s] = e; ps += e; }
  red[t] = ps; __syncthreads();
  for(int s2 = 128; s2 > 0; s2 >>= 1){ if(t < s2) red[t] += red[t+s2]; __syncthreads(); }
  float inv = 1.f / red[0];
  __syncthreads();
  float acc = 0.f;
  for(int s = 0; s < 500; ++s) acc += lg[s] * xb[(size_t)s*256 + t];
  acc *= inv;
  __syncthreads();
  red[t] = acc; __syncthreads();
  for(int s2 = 128; s2 > 0; s2 >>= 1){ if(t < s2) red[t] += red[t+s2]; __syncthreads(); }
  float mean = red[0] / 256.f; __syncthreads();
  float d = acc - mean;
  red[t] = d*d; __syncthreads();
  for(int s2 = 128; s2 > 0; s2 >>= 1){ if(t < s2) red[t] += red[t+s2]; __syncthreads(); }
  float rstd = 1.f / sqrtf(red[0]/256.f + 1e-5f);
  __syncthreads();
  float val = (d*rstd*og[t] + ob[t]) * ohW[t];
  red[t] = val; __syncthreads();
  for(int s2 = 128; s2 > 0; s2 >>= 1){ if(t < s2) red[t] += red[t+s2]; __syncthreads(); }
  if(t == 0) out[b] = red[0] + ohb[0];
}

extern "C" void kernel_launch(void* const* d_in, const int* in_sizes, int n_in,
                              void* d_out, int out_size, void* d_ws, size_t ws_size,
                              hipStream_t stream){
  const float* mel      = (const float*)d_in[0];
  const int*   events   = (const int*)d_in[1];
  const unsigned char* emask = (const unsigned char*)d_in[2];
  const float* star     = (const float*)d_in[3];
  const float* mel_W    = (const float*)d_in[4];
  const float* mel_b    = (const float*)d_in[5];
  const float* conv1_w  = (const float*)d_in[6];
  const float* conv1_b  = (const float*)d_in[7];
  const float* gn_g     = (const float*)d_in[8];
  const float* gn_b     = (const float*)d_in[9];
  const float* conv2_w  = (const float*)d_in[10];
  const float* conv2_b  = (const float*)d_in[11];
  const float* cn_g     = (const float*)d_in[12];
  const float* cn_b     = (const float*)d_in[13];
  const float* star_tab = (const float*)d_in[14];
  const float* ep_W1    = (const float*)d_in[15];
  const float* ep_b1    = (const float*)d_in[16];
  const float* ep_W2    = (const float*)d_in[17];
  const float* ep_b2    = (const float*)d_in[18];
  const float* tl_Wqkv  = (const float*)d_in[19];
  const float* tl_bqkv  = (const float*)d_in[20];
  const float* tl_Wo    = (const float*)d_in[21];
  const float* tl_bo    = (const float*)d_in[22];
  const float* tl_ln1g  = (const float*)d_in[23];
  const float* tl_ln1b  = (const float*)d_in[24];
  const float* tl_ln2g  = (const float*)d_in[25];
  const float* tl_ln2b  = (const float*)d_in[26];
  const float* tl_W1    = (const float*)d_in[27];
  const float* tl_b1    = (const float*)d_in[28];
  const float* tl_W2    = (const float*)d_in[29];
  const float* tl_b2    = (const float*)d_in[30];
  const float* pool_q   = (const float*)d_in[31];
  const float* on_g     = (const float*)d_in[32];
  const float* on_b     = (const float*)d_in[33];
  const float* oh_W     = (const float*)d_in[34];
  const float* oh_b     = (const float*)d_in[35];
  (void)in_sizes; (void)n_in; (void)out_size; (void)ws_size;

  float* ws  = (float*)d_ws;
  float* X   = ws;                        // fp32 (B,S,256)
  short* XNB = (short*)(ws + 4096000);    // bf16 (B,S,256) (layer-0 input only)
  short* OB  = (short*)(ws + 6144000);    // bf16 attn out (B,S,256)
  short* WB  = (short*)(ws + 8192000);    // bf16 weights
  float* BIG = ws + 10812000;             // scratch
  double* PART = (double*)(ws + 28668000);
  float* STATS = ws + 28671900;

  // WB sub-offsets (shorts)
  short* WBc1 = WB + 0;         // 128x128
  short* WBc2 = WB + 16384;     // 256x896
  short* WBe1 = WB + 245760;    // 256x768
  short* WBe2 = WB + 442368;    // 256x256
  short* WBqk = WB + 507904;    // 6 x 768x256
  short* WBwo = WB + 1687552;   // 6 x 256x256
  short* WBw1 = WB + 2080768;   // 6 x 1024x256
  short* WBw2 = WB + 3653632;   // 6 x 256x1024

  // BIG sub-layouts
  float* XMEL = BIG;                       // (B,16,2000)
  short* A1B  = (short*)(BIG + 1024000);   // (32000,128) bf16
  float* H1   = BIG + 3072000;             // (B,1000,128)
  short* A2B  = (short*)(BIG + 7168000);   // (16000,896) bf16
  float* XPRE = BIG;                       // (B,S,256)
  short* COMBB= (short*)BIG;               // (8192,768) bf16
  short* EHIDB= (short*)(BIG + 3146000);   // (8192,256) bf16
  float* EVO  = BIG + 4195000;             // (8192,256) fp32
  short* QKVB = (short*)BIG;               // (16000,768) bf16
  short* HIDB = (short*)(BIG + 7168000);   // (16000,1024) bf16

  // ---- weight conversion (fused) ----
  conv1w_pad<<<128, 128, 0, stream>>>(conv1_w, WBc1);
  f2b_all<<<20352, 256, 0, stream>>>(conv2_w, ep_W1, ep_W2, tl_Wqkv, tl_Wo, tl_W1, tl_W2, WB);

  // ---- prologue ----
  mel_kernel<<<kB*8, 256, 0, stream>>>(mel, mel_W, mel_b, XMEL);
  im2col1b<<<16000, 256, 0, stream>>>(XMEL, A1B);
  gemm_mfma<0,true><<<dim3(1, 250), 256, 0, stream>>>(A1B, WBc1, conv1_b, H1, 32000, 128, 128);
  gn_part<<<256, 256, 0, stream>>>(H1, PART);
  gn_final<<<1, 256, 0, stream>>>(PART, STATS);
  im2col2b<<<56000, 256, 0, stream>>>(H1, STATS, gn_g, gn_b, A2B);
  gemm_mfma<0,true><<<dim3(2, 125), 256, 0, stream>>>(A2B, WBc2, conv2_b, XPRE, 16000, 256, 896);
  postconv<<<16000, 256, 0, stream>>>(XPRE, cn_g, cn_b, star, star_tab, X);
  // events
  event_feat<<<kB*256, 256, 0, stream>>>(events, COMBB);
  gemm_mfma<2,true><<<dim3(2, 64), 256, 0, stream>>>(COMBB, WBe1, ep_b1, EHIDB, 8192, 256, 768);
  gemm_mfma<0,false><<<dim3(2, 64), 256, 0, stream>>>(EHIDB, WBe2, ep_b2, EVO, 8192, 256, 256);
  ev_scatter<<<kB*256, 256, 0, stream>>>(EVO, events, emask, X);

  // ---- transformer layers ----
  ln_rows<<<16000, 256, 0, stream>>>(X, tl_ln1g, tl_ln1b, XNB);   // ln1[0]
  gemm512<false><<<dim3(3, 125), 512, 0, stream>>>(XNB, WBqk, tl_bqkv, QKVB, 16000, 768, 256);  // QKV layer 0
  for(int i = 0; i < 6; ++i){
    attn_mfma<<<512, 512, 0, stream>>>(QKVB, OB);
    // Wo + resid + LN2 -> (LDS) -> W1 + GELU -> HIDB
    gemm_fused<true><<<250, 512, 0, stream>>>(OB, WBwo + (size_t)i*65536, tl_bo + i*256,
        X, tl_ln2g + i*256, tl_ln2b + i*256,
        WBw1 + (size_t)i*262144, tl_b1 + i*1024, HIDB, 16000, 256, 1024);
    if(i < 5)
      // W2 + resid + LN1[i+1] -> (LDS) -> QKV[i+1] -> QKVB
      gemm_fused<false><<<250, 512, 0, stream>>>(HIDB, WBw2 + (size_t)i*262144, tl_b2 + i*256,
          X, tl_ln1g + (i+1)*256, tl_ln1b + (i+1)*256,
          WBqk + (size_t)(i+1)*196608, tl_bqkv + (i+1)*768, QKVB, 16000, 1024, 768);
    else
      gemm_ln<false><<<dim3(1, 250), 512, 0, stream>>>(HIDB, WBw2 + (size_t)i*262144, tl_b2 + i*256,
          X, tl_ln1g, tl_ln1b, XNB, 16000, 1024);
  }

  // ---- pooling + head ----
  pool_head<<<kB, 256, 0, stream>>>(X, pool_q, on_g, on_b, oh_W, oh_b, (float*)d_out);
}

// Round 14
// 844.340 us; speedup vs baseline: 1.0301x; 1.0301x over previous
//
#include <hip/hip_runtime.h>
#include <math.h>

namespace {
constexpr int kB = 32;
constexpr int kS = 500;
constexpr int kH = 8;
}
// -ln(10000)/127
#define LKC (-0.07252236513366287)

typedef __attribute__((ext_vector_type(8))) short s16x8;
typedef __attribute__((ext_vector_type(4))) float f32x4;

__device__ __forceinline__ float gelu_f(float x){
  return 0.5f * x * (1.0f + erff(x * 0.7071067811865476f));
}
__device__ __forceinline__ float b2f(short s){
  union { unsigned u; float f; } x; x.u = ((unsigned)(unsigned short)s) << 16; return x.f;
}
__device__ __forceinline__ short f2b(float f){
  unsigned u = __float_as_uint(f);
  unsigned r = (u + 0x7fffu + ((u >> 16) & 1u)) >> 16;
  return (short)r;
}
// packed 2xfp32 -> 2xbf16 (RNE), D.lo = S0
__device__ __forceinline__ unsigned cvtpk(float lo, float hi){
  unsigned r;
  asm("v_cvt_pk_bf16_f32 %0, %1, %2" : "=v"(r) : "v"(lo), "v"(hi));
  return r;
}

// conv1 weight: (128,112) -> bf16 padded to (128,128)
__global__ __launch_bounds__(128) void conv1w_pad(const float* __restrict__ w, short* __restrict__ out){
  int n = blockIdx.x, k = threadIdx.x;
  out[n*128 + k] = (k < 112) ? f2b(w[n*112 + k]) : (short)0;
}

// ---------------- fused fp32 -> bf16 weight conversion (7 arrays, 1 launch) ----------------
__global__ __launch_bounds__(256) void f2b_all(const float* __restrict__ c2,
    const float* __restrict__ e1, const float* __restrict__ e2,
    const float* __restrict__ qk, const float* __restrict__ wo,
    const float* __restrict__ w1, const float* __restrict__ w2,
    short* __restrict__ WB){
  int blk = blockIdx.x, t = threadIdx.x;
  const float* src; short* dst; int idx;
  if(blk < 896){        src = c2; dst = WB + 16384;   idx = blk*256 + t; }
  else if(blk < 1664){  src = e1; dst = WB + 245760;  idx = (blk-896)*256 + t; }
  else if(blk < 1920){  src = e2; dst = WB + 442368;  idx = (blk-1664)*256 + t; }
  else if(blk < 6528){  src = qk; dst = WB + 507904;  idx = (blk-1920)*256 + t; }
  else if(blk < 8064){  src = wo; dst = WB + 1687552; idx = (blk-6528)*256 + t; }
  else if(blk < 14208){ src = w1; dst = WB + 2080768; idx = (blk-8064)*256 + t; }
  else {                src = w2; dst = WB + 3653632; idx = (blk-14208)*256 + t; }
  dst[idx] = f2b(src[idx]);
}

// ---------------- MFMA GEMM (256 thr, 128x128 tile): prologue/event GEMMs ----------------
template<int OUT, bool DOGELU>
__global__ __launch_bounds__(256) void gemm_mfma(const short* __restrict__ A,
    const short* __restrict__ W, const float* __restrict__ bias,
    void* __restrict__ Cv, int M, int N, int K){
  __shared__ __align__(16) short Al[128*64];
  __shared__ __align__(16) short Wl[128*64];
  const int t = threadIdx.x;
  const int wid = t >> 6, lane = t & 63;
  const int m0 = blockIdx.y * 128, n0 = blockIdx.x * 128;
  const int wr = (wid >> 1) * 64, wc = (wid & 1) * 64;
  const int frow = lane & 15, lg = lane >> 4;
  const int rA = t >> 3;
  const int sA = (t & 7) ^ (rA & 7);
  const short* Aq = A + (size_t)(m0 + rA) * K + sA * 8;
  const short* Wq = W + (size_t)(n0 + rA) * K + sA * 8;
  f32x4 acc[4][4] = {};
  for(int k0 = 0; k0 < K; k0 += 64){
    s16x8 av[4], wv[4];
    #pragma unroll
    for(int j = 0; j < 4; ++j){
      av[j] = *(const s16x8*)(Aq + k0 + (size_t)(32*j)*K);
      wv[j] = *(const s16x8*)(Wq + k0 + (size_t)(32*j)*K);
    }
    __syncthreads();
    #pragma unroll
    for(int j = 0; j < 4; ++j){
      *(s16x8*)&Al[t*8 + j*2048] = av[j];
      *(s16x8*)&Wl[t*8 + j*2048] = wv[j];
    }
    __syncthreads();
    #pragma unroll
    for(int kh = 0; kh < 2; ++kh){
      s16x8 a[4], b[4];
      #pragma unroll
      for(int mi = 0; mi < 4; ++mi){
        int r = wr + mi*16 + frow;
        a[mi] = *(const s16x8*)&Al[r*64 + (((kh*4 + lg) ^ (r & 7)) * 8)];
      }
      #pragma unroll
      for(int ni = 0; ni < 4; ++ni){
        int r = wc + ni*16 + frow;
        b[ni] = *(const s16x8*)&Wl[r*64 + (((kh*4 + lg) ^ (r & 7)) * 8)];
      }
      #pragma unroll
      for(int mi = 0; mi < 4; ++mi)
        #pragma unroll
        for(int ni = 0; ni < 4; ++ni)
          acc[mi][ni] = __builtin_amdgcn_mfma_f32_16x16x32_bf16(a[mi], b[ni], acc[mi][ni], 0, 0, 0);
    }
  }
  #pragma unroll
  for(int mi = 0; mi < 4; ++mi){
    #pragma unroll
    for(int ni = 0; ni < 4; ++ni){
      const int col = n0 + wc + ni*16 + (lane & 15);
      const float bv = bias[col];
      #pragma unroll
      for(int r = 0; r < 4; ++r){
        const int row = m0 + wr + mi*16 + (lane >> 4)*4 + r;
        float v = acc[mi][ni][r] + bv;
        if(DOGELU) v = gelu_f(v);
        if(OUT == 0) ((float*)Cv)[(size_t)row*N + col] = v;
        else if(OUT == 1) ((float*)Cv)[(size_t)row*N + col] += v;
        else ((short*)Cv)[(size_t)row*N + col] = f2b(v);
      }
    }
  }
}

// ---------------- gemm512: 128Mx256N tile, 512 threads (8 waves of 64x64), BK=64 ----------------
template<bool DOGELU>
__global__ __launch_bounds__(512) void gemm512(const short* __restrict__ A,
    const short* __restrict__ W, const float* __restrict__ bias,
    short* __restrict__ C, int M, int N, int K){
  __shared__ __align__(16) short Al[128*64];
  __shared__ __align__(16) short Wl[256*64];
  const int t = threadIdx.x;
  const int wid = t >> 6, lane = t & 63;
  const int m0 = blockIdx.y * 128, n0 = blockIdx.x * 256;
  const int wm = wid >> 2, wn = wid & 3;
  const int frow = lane & 15, lg = lane >> 4;
  const int rA = t >> 3;
  const int sA = (t & 7) ^ (rA & 7);
  const short* Aq = A + (size_t)(m0 + rA) * K + sA * 8;
  const short* Wq = W + (size_t)(n0 + rA) * K + sA * 8;
  f32x4 acc[4][4] = {};
  for(int k0 = 0; k0 < K; k0 += 64){
    s16x8 av[2], wv[4];
    av[0] = *(const s16x8*)(Aq + k0);
    av[1] = *(const s16x8*)(Aq + k0 + (size_t)64*K);
    #pragma unroll
    for(int j = 0; j < 4; ++j)
      wv[j] = *(const s16x8*)(Wq + k0 + (size_t)(64*j)*K);
    __syncthreads();
    *(s16x8*)&Al[t*8] = av[0];
    *(s16x8*)&Al[t*8 + 4096] = av[1];
    #pragma unroll
    for(int j = 0; j < 4; ++j)
      *(s16x8*)&Wl[t*8 + j*4096] = wv[j];
    __syncthreads();
    #pragma unroll
    for(int kh = 0; kh < 2; ++kh){
      s16x8 a[4], b[4];
      #pragma unroll
      for(int mi = 0; mi < 4; ++mi){
        int r = wm*64 + mi*16 + frow;
        a[mi] = *(const s16x8*)&Al[r*64 + (((kh*4 + lg) ^ (r & 7)) * 8)];
      }
      #pragma unroll
      for(int ni = 0; ni < 4; ++ni){
        int r = wn*64 + ni*16 + frow;
        b[ni] = *(const s16x8*)&Wl[r*64 + (((kh*4 + lg) ^ (r & 7)) * 8)];
      }
      #pragma unroll
      for(int mi = 0; mi < 4; ++mi)
        #pragma unroll
        for(int ni = 0; ni < 4; ++ni)
          acc[mi][ni] = __builtin_amdgcn_mfma_f32_16x16x32_bf16(a[mi], b[ni], acc[mi][ni], 0, 0, 0);
    }
  }
  #pragma unroll
  for(int mi = 0; mi < 4; ++mi){
    #pragma unroll
    for(int ni = 0; ni < 4; ++ni){
      const int col = n0 + wn*64 + ni*16 + (lane & 15);
      const float bv = bias[col];
      #pragma unroll
      for(int r = 0; r < 4; ++r){
        const int row = m0 + wm*64 + mi*16 + (lane >> 4)*4 + r;
        float v = acc[mi][ni][r] + bv;
        if(DOGELU) v = gelu_f(v);
        C[(size_t)row*N + col] = f2b(v);
      }
    }
  }
}

// ---------------- gemm_ln: 64Mx256N, N==256: X += A@W^T+bias; optional row-LN -> XNB ----------------
template<bool DOLN>
__global__ __launch_bounds__(512) void gemm_ln(const short* __restrict__ A,
    const short* __restrict__ W, const float* __restrict__ bias,
    float* __restrict__ X, const float* __restrict__ lg_, const float* __restrict__ lb_,
    short* __restrict__ XNB, int M, int K){
  __shared__ __align__(16) short Al[64*64];
  __shared__ __align__(16) short Wl[256*64];
  __shared__ float sbuf[64][4];
  const int t = threadIdx.x;
  const int wid = t >> 6, lane = t & 63;
  const int m0 = blockIdx.y * 64;
  const int wm = wid >> 2, wn = wid & 3;
  const int frow = lane & 15, lg = lane >> 4;
  const int lq = lane & 15;
  const int rA = t >> 3;
  const int sA = (t & 7) ^ (rA & 7);
  const short* Aq = A + (size_t)(m0 + rA) * K + sA * 8;
  const short* Wq = W + (size_t)rA * K + sA * 8;
  f32x4 acc[2][4] = {};
  for(int k0 = 0; k0 < K; k0 += 64){
    s16x8 av = *(const s16x8*)(Aq + k0);
    s16x8 wv[4];
    #pragma unroll
    for(int j = 0; j < 4; ++j)
      wv[j] = *(const s16x8*)(Wq + k0 + (size_t)(64*j)*K);
    __syncthreads();
    *(s16x8*)&Al[t*8] = av;
    #pragma unroll
    for(int j = 0; j < 4; ++j)
      *(s16x8*)&Wl[t*8 + j*4096] = wv[j];
    __syncthreads();
    #pragma unroll
    for(int kh = 0; kh < 2; ++kh){
      s16x8 a[2], b[4];
      #pragma unroll
      for(int mi = 0; mi < 2; ++mi){
        int r = wm*32 + mi*16 + frow;
        a[mi] = *(const s16x8*)&Al[r*64 + (((kh*4 + lg) ^ (r & 7)) * 8)];
      }
      #pragma unroll
      for(int ni = 0; ni < 4; ++ni){
        int r = wn*64 + ni*16 + frow;
        b[ni] = *(const s16x8*)&Wl[r*64 + (((kh*4 + lg) ^ (r & 7)) * 8)];
      }
      #pragma unroll
      for(int mi = 0; mi < 2; ++mi)
        #pragma unroll
        for(int ni = 0; ni < 4; ++ni)
          acc[mi][ni] = __builtin_amdgcn_mfma_f32_16x16x32_bf16(a[mi], b[ni], acc[mi][ni], 0, 0, 0);
    }
  }
  // v = acc + bias + residual
  float v[2][4][4];
  #pragma unroll
  for(int mi = 0; mi < 2; ++mi)
    #pragma unroll
    for(int ni = 0; ni < 4; ++ni){
      const int col = wn*64 + ni*16 + lq;
      const float bv = bias[col];
      #pragma unroll
      for(int r = 0; r < 4; ++r){
        const int row = m0 + wm*32 + mi*16 + lg*4 + r;
        v[mi][ni][r] = acc[mi][ni][r] + bv + X[(size_t)row*256 + col];
      }
    }
  __syncthreads();
  float vmean[2][4], vrstd[2][4];
  if(DOLN){
    #pragma unroll
    for(int mi = 0; mi < 2; ++mi)
      #pragma unroll
      for(int r = 0; r < 4; ++r){
        float s = v[mi][0][r] + v[mi][1][r] + v[mi][2][r] + v[mi][3][r];
        s += __shfl_xor(s, 1); s += __shfl_xor(s, 2);
        s += __shfl_xor(s, 4); s += __shfl_xor(s, 8);
        if(lq == 0) sbuf[wm*32 + mi*16 + lg*4 + r][wn] = s;
      }
    __syncthreads();
    #pragma unroll
    for(int mi = 0; mi < 2; ++mi)
      #pragma unroll
      for(int r = 0; r < 4; ++r){
        int rl = wm*32 + mi*16 + lg*4 + r;
        vmean[mi][r] = (sbuf[rl][0] + sbuf[rl][1] + sbuf[rl][2] + sbuf[rl][3]) * (1.f/256.f);
      }
    __syncthreads();
    #pragma unroll
    for(int mi = 0; mi < 2; ++mi)
      #pragma unroll
      for(int r = 0; r < 4; ++r){
        float q = 0.f;
        #pragma unroll
        for(int ni = 0; ni < 4; ++ni){ float d = v[mi][ni][r] - vmean[mi][r]; q += d*d; }
        q += __shfl_xor(q, 1); q += __shfl_xor(q, 2);
        q += __shfl_xor(q, 4); q += __shfl_xor(q, 8);
        if(lq == 0) sbuf[wm*32 + mi*16 + lg*4 + r][wn] = q;
      }
    __syncthreads();
    #pragma unroll
    for(int mi = 0; mi < 2; ++mi)
      #pragma unroll
      for(int r = 0; r < 4; ++r){
        int rl = wm*32 + mi*16 + lg*4 + r;
        float Q = sbuf[rl][0] + sbuf[rl][1] + sbuf[rl][2] + sbuf[rl][3];
        vrstd[mi][r] = 1.f / sqrtf(Q * (1.f/256.f) + 1e-5f);
      }
  }
  #pragma unroll
  for(int mi = 0; mi < 2; ++mi)
    #pragma unroll
    for(int ni = 0; ni < 4; ++ni){
      const int col = wn*64 + ni*16 + lq;
      float gg = 0.f, bb = 0.f;
      if(DOLN){ gg = lg_[col]; bb = lb_[col]; }
      #pragma unroll
      for(int r = 0; r < 4; ++r){
        const int row = m0 + wm*32 + mi*16 + lg*4 + r;
        float val = v[mi][ni][r];
        X[(size_t)row*256 + col] = val;
        if(DOLN)
          XNB[(size_t)row*256 + col] = f2b((val - vmean[mi][r]) * vrstd[mi][r] * gg + bb);
      }
    }
}

// ---------------- mel compress: (B,80,2000) -> (B,16,2000) ----------------
__global__ __launch_bounds__(256) void mel_kernel(const float* __restrict__ mel,
    const float* __restrict__ W, const float* __restrict__ bias, float* __restrict__ xm){
  __shared__ float Ws[16][80];
  __shared__ float bs[16];
  const int t = threadIdx.x;
  for(int i = t; i < 16*80; i += 256) Ws[i/80][i%80] = W[i];
  if(t < 16) bs[t] = bias[t];
  __syncthreads();
  int blk = blockIdx.x;
  int b = blk >> 3;
  int tc = (blk & 7) * 256 + t;
  if(tc >= 2000) return;
  float acc[16];
  #pragma unroll
  for(int o = 0; o < 16; ++o) acc[o] = bs[o];
  for(int c = 0; c < 80; ++c){
    float v = mel[((size_t)b*80 + c)*2000 + tc];
    #pragma unroll
    for(int o = 0; o < 16; ++o) acc[o] += v * Ws[o][c];
  }
  #pragma unroll
  for(int o = 0; o < 16; ++o) xm[((size_t)b*16 + o)*2000 + tc] = acc[o];
}

// ---------------- im2col conv1 -> bf16, K padded to 128 ----------------
__global__ __launch_bounds__(256) void im2col1b(const float* __restrict__ xm, short* __restrict__ A){
  size_t idx = (size_t)blockIdx.x * 256 + threadIdx.x; // 32000*128
  int col = idx & 127;
  size_t row = idx >> 7;
  int t1 = row % 1000, b = row / 1000;
  float v = 0.f;
  if(col < 112){
    int i = col / 7, k = col % 7;
    int src = 2*t1 + k - 3;
    if(src >= 0 && src < 2000) v = xm[((size_t)b*16 + i)*2000 + src];
  }
  A[idx] = f2b(v);
}

// ---------------- GroupNorm(1) stats: two-stage ----------------
__global__ __launch_bounds__(256) void gn_part(const float* __restrict__ h1, double* __restrict__ part){
  int blk = blockIdx.x;  // 256 = 32 b x 8 segs
  const float* p = h1 + (size_t)blk * 16000;
  int t = threadIdx.x;
  double s = 0, q = 0;
  for(int i = t; i < 16000; i += 256){ double v = p[i]; s += v; q += v*v; }
  __shared__ double rs[256], rq[256];
  rs[t] = s; rq[t] = q; __syncthreads();
  for(int s2 = 128; s2 > 0; s2 >>= 1){
    if(t < s2){ rs[t] += rs[t+s2]; rq[t] += rq[t+s2]; }
    __syncthreads();
  }
  if(t == 0){ part[blk*2] = rs[0]; part[blk*2+1] = rq[0]; }
}
__global__ __launch_bounds__(256) void gn_final(const double* __restrict__ part, float* __restrict__ stats){
  int t = threadIdx.x;     // 256 = 32 b x 8
  int b = t >> 3;
  double s = part[t*2], q = part[t*2+1];
  s += __shfl_xor(s, 1); q += __shfl_xor(q, 1);
  s += __shfl_xor(s, 2); q += __shfl_xor(q, 2);
  s += __shfl_xor(s, 4); q += __shfl_xor(q, 4);
  if((t & 7) == 0){
    double mean = s / 128000.0;
    double var  = q / 128000.0 - mean*mean;
    stats[b*2]   = (float)mean;
    stats[b*2+1] = (float)(1.0 / sqrt(var + 1e-5));
  }
}

// ---------------- im2col conv2 (fused GroupNorm) -> bf16 ----------------
__global__ __launch_bounds__(256) void im2col2b(const float* __restrict__ h1,
    const float* __restrict__ stats, const float* __restrict__ gg,
    const float* __restrict__ gb, short* __restrict__ A){
  size_t idx = (size_t)blockIdx.x * 256 + threadIdx.x; // 16000*896
  int col = idx % 896;
  size_t row = idx / 896;
  int t2 = row % 500, b = row / 500;
  int i = col / 7, k = col % 7;
  int src = 2*t2 + k - 3;
  float v = 0.f;
  if(src >= 0 && src < 1000){
    float raw = h1[((size_t)b*1000 + src)*128 + i];
    v = (raw - stats[b*2]) * stats[b*2+1] * gg[i] + gb[i];
  }
  A[idx] = f2b(v);
}

// ---------------- post-conv: LN(D) + sinpos + star table -> X (fp32) ----------------
__global__ __launch_bounds__(256) void postconv(const float* __restrict__ xp,
    const float* __restrict__ cg, const float* __restrict__ cb,
    const float* __restrict__ star, const float* __restrict__ stab,
    float* __restrict__ x){
  int row = blockIdx.x, t = threadIdx.x;
  int s = row % 500, b = row / 500;
  __shared__ float red[256];
  float v = xp[(size_t)row*256 + t];
  red[t] = v; __syncthreads();
  for(int s2 = 128; s2 > 0; s2 >>= 1){ if(t < s2) red[t] += red[t+s2]; __syncthreads(); }
  float mean = red[0] / 256.f; __syncthreads();
  float d = v - mean;
  red[t] = d*d; __syncthreads();
  for(int s2 = 128; s2 > 0; s2 >>= 1){ if(t < s2) red[t] += red[t+s2]; __syncthreads(); }
  float rstd = 1.f / sqrtf(red[0]/256.f + 1e-5f);
  int j = t & 127;
  double f = exp((double)j * LKC);
  double a = (double)s * f;
  float pe = (float)(t < 128 ? sin(a) : cos(a));
  int bucket = (int)(star[b] * 2.0f);
  bucket = bucket < 0 ? 0 : (bucket > 19 ? 19 : bucket);
  x[(size_t)row*256 + t] = d*rstd*cg[t] + cb[t] + pe + stab[bucket*256 + t];
}

// ---------------- event features -> combined bf16 (B*NEV, 768) ----------------
__global__ __launch_bounds__(256) void event_feat(const int* __restrict__ events, short* __restrict__ comb){
  int blk = blockIdx.x;           // 8192
  int e = blk & 255, b = blk >> 8;
  const int* ev = events + b*256;
  int t = threadIdx.x;
  auto gof = [&](int i){ int j = i < 1 ? 1 : i; int d = ev[j] - ev[j-1]; return d < 1 ? 1 : d; };
  int gi = gof(e);
  double rb = 1.0, ra = 1.0;
  if(e != 0){
    rb = (double)gi / (double)gof(e-1);
    rb = rb < 0.1 ? 0.1 : (rb > 10.0 ? 10.0 : rb);
  }
  if(e != 255){
    ra = (double)gof(e+1) / (double)gi;
    ra = ra < 0.1 ? 0.1 : (ra > 10.0 ? 10.0 : ra);
  }
  int rbi = (int)(rb * 50.0);
  int rai = (int)(ra * 50.0);
  int gap = 5 * gi;
  int j = t & 127;
  double f = exp((double)j * LKC);
  double a0 = (double)rbi * f, a1 = (double)rai * f, a2 = (double)gap * f;
  size_t base = (size_t)blk * 768;
  comb[base + t]       = f2b((float)(t < 128 ? sin(a0) : cos(a0)));
  comb[base + 256 + t] = f2b((float)(t < 128 ? sin(a1) : cos(a1)));
  comb[base + 512 + t] = f2b((float)(t < 128 ? sin(a2) : cos(a2)));
}

// ---------------- scatter-add events into X ----------------
__global__ __launch_bounds__(256) void ev_scatter(const float* __restrict__ evout,
    const int* __restrict__ events, const unsigned char* __restrict__ mask,
    float* __restrict__ x){
  int blk = blockIdx.x; // 8192
  int e = blk & 255, b = blk >> 8;
  if(mask[b*256 + e]) return;
  int tp = events[b*256 + e] >> 2;
  tp = tp < 0 ? 0 : (tp > 499 ? 499 : tp);
  int t = threadIdx.x;
  atomicAdd(&x[((size_t)b*500 + tp)*256 + t], evout[(size_t)blk*256 + t]);
}

// ---------------- LayerNorm rows of 256 -> bf16 (wave-shuffle reduce) ----------------
__global__ __launch_bounds__(256) void ln_rows(const float* __restrict__ x,
    const float* __restrict__ g, const float* __restrict__ b, short* __restrict__ out){
  int row = blockIdx.x, t = threadIdx.x;
  int wid = t >> 6, lane = t & 63;
  __shared__ float sm[8];
  float v = x[(size_t)row*256 + t];
  float s = v;
  #pragma unroll
  for(int o = 1; o < 64; o <<= 1) s += __shfl_xor(s, o);
  if(lane == 0) sm[wid] = s;
  __syncthreads();
  float mean = (sm[0] + sm[1] + sm[2] + sm[3]) * (1.f/256.f);
  float d = v - mean;
  float q = d*d;
  #pragma unroll
  for(int o = 1; o < 64; o <<= 1) q += __shfl_xor(q, o);
  if(lane == 0) sm[4 + wid] = q;
  __syncthreads();
  float rstd = 1.f / sqrtf((sm[4] + sm[5] + sm[6] + sm[7]) * (1.f/256.f) + 1e-5f);
  out[(size_t)row*256 + t] = f2b(d*rstd*g[t] + b[t]);
}

// ---------------- MFMA flash attention: split-q, two-pass K halves ----------------
// grid 512 = (XCD-swizzled b, h, q-half); 512 threads; LDS 56.5KB -> 2 blocks/CU (4 waves/SIMD).
// No-max exp2 softmax => exact accumulation across the two 256-key passes (no merge).
__global__ __launch_bounds__(512) void attn_mfma(const short* __restrict__ qkv,
    short* __restrict__ o){
  __shared__ __align__(16) short Kl[256*40];      // 20 KB
  __shared__ __align__(16) short Vt[32*264];      // 16.5 KB
  __shared__ __align__(16) short Pl[8][2][640];   // 20 KB (double-buffered per wave)
  const int i = blockIdx.x;
  const int b = (i & 7)*4 + ((i >> 3) & 3);       // same b -> same XCD
  const int qh = (i >> 5) & 1;                    // q-half
  const int h = (i >> 6) & 7;
  const int t = threadIdx.x;
  const int wid = t >> 6, lane = t & 63;
  const int lq = lane & 15, lg = lane >> 4;
  const short* base = qkv + (size_t)b * kS * 768;
  const float c2 = 0.17677669529663687f * 1.4426950408889634f;
  s16x8 qf[2];
  #pragma unroll
  for(int qi = 0; qi < 2; ++qi){
    int qrow = (qh*16 + wid*2 + qi)*16 + lq;
    if(qrow > kS-1) qrow = kS-1;
    qf[qi] = *(const s16x8*)(base + (size_t)qrow*768 + h*32 + lg*8);
  }
  float lsum[2] = {0.f, 0.f};
  f32x4 oa0[2] = {}, oa1[2] = {};
  for(int khalf = 0; khalf < 2; ++khalf){
    const int k0base = khalf * 256;
    if(khalf) __syncthreads();
    {
      const int c = t & 3;
      for(int idx = t; idx < 1024; idx += 512){
        int row = idx >> 2;
        int grow = k0base + row;
        s16x8 kv = {0,0,0,0,0,0,0,0};
        unsigned vu0 = 0, vu1 = 0, vu2 = 0, vu3 = 0;
        if(grow < kS){
          const short* rp = base + (size_t)grow*768 + 256 + h*32 + c*8;
          kv = *(const s16x8*)rp;
          uint4 vv = *(const uint4*)(rp + 256);
          vu0 = vv.x; vu1 = vv.y; vu2 = vv.z; vu3 = vv.w;
        }
        *(s16x8*)&Kl[row*40 + c*8] = kv;
        unsigned b0 = (c & 2) ? vu2 : vu0, b1 = (c & 2) ? vu3 : vu1;
        unsigned b2 = (c & 2) ? vu0 : vu2, b3 = (c & 2) ? vu1 : vu3;
        unsigned r0 = (c & 1) ? b1 : b0, r1 = (c & 1) ? b2 : b1;
        unsigned r2 = (c & 1) ? b3 : b2, r3 = (c & 1) ? b0 : b3;
        #pragma unroll
        for(int j0 = 0; j0 < 8; ++j0){
          unsigned w = (j0 >> 1) == 0 ? r0 : (j0 >> 1) == 1 ? r1 : (j0 >> 1) == 2 ? r2 : r3;
          short val = (short)((j0 & 1) ? (w >> 16) : (w & 0xffff));
          int d = c*8 + ((j0 + 2*c) & 7);
          Vt[d*264 + row] = val;
        }
      }
    }
    __syncthreads();
    #pragma unroll
    for(int qi = 0; qi < 2; ++qi){
      f32x4 sc[16];
      __builtin_amdgcn_s_setprio(1);
      #pragma unroll
      for(int kt = 0; kt < 16; ++kt){
        s16x8 kf = *(const s16x8*)&Kl[(kt*16 + lq)*40 + lg*8];
        f32x4 z = {0.f,0.f,0.f,0.f};
        sc[kt] = __builtin_amdgcn_mfma_f32_16x16x32_bf16(kf, qf[qi], z, 0, 0, 0);
      }
      __builtin_amdgcn_s_setprio(0);
      if(khalf == 1 && lg >= 1){ sc[15][0] = -1e30f; sc[15][1] = -1e30f; sc[15][2] = -1e30f; sc[15][3] = -1e30f; }
      float l0 = 0.f, l1 = 0.f, l2 = 0.f, l3 = 0.f;
      #pragma unroll
      for(int kt = 0; kt < 16; ++kt){
        float p0 = exp2f(sc[kt][0] * c2);
        float p1 = exp2f(sc[kt][1] * c2);
        float p2 = exp2f(sc[kt][2] * c2);
        float p3 = exp2f(sc[kt][3] * c2);
        sc[kt][0] = p0; sc[kt][1] = p1; sc[kt][2] = p2; sc[kt][3] = p3;
        l0 += p0; l1 += p1; l2 += p2; l3 += p3;
      }
      lsum[qi] += (l0 + l1) + (l2 + l3);
      #pragma unroll
      for(int kt2 = 0; kt2 < 8; ++kt2){
        short* pw = &Pl[wid][kt2 & 1][0];
        f32x4 p0 = sc[kt2*2], p1 = sc[kt2*2+1];
        uint2 pk0, pk1;
        pk0.x = cvtpk(p0[0], p0[1]); pk0.y = cvtpk(p0[2], p0[3]);
        pk1.x = cvtpk(p1[0], p1[1]); pk1.y = cvtpk(p1[2], p1[3]);
        *(uint2*)&pw[lq*40 + lg*4] = pk0;
        *(uint2*)&pw[lq*40 + 16 + lg*4] = pk1;
        s16x8 pf = *(const s16x8*)&pw[lq*40 + lg*8];
        s16x8 v0 = *(const s16x8*)&Vt[lq*264 + kt2*32 + lg*8];
        s16x8 v1 = *(const s16x8*)&Vt[(16+lq)*264 + kt2*32 + lg*8];
        __builtin_amdgcn_s_setprio(1);
        oa0[qi] = __builtin_amdgcn_mfma_f32_16x16x32_bf16(v0, pf, oa0[qi], 0, 0, 0);
        oa1[qi] = __builtin_amdgcn_mfma_f32_16x16x32_bf16(v1, pf, oa1[qi], 0, 0, 0);
        __builtin_amdgcn_s_setprio(0);
      }
    }
  }
  #pragma unroll
  for(int qi = 0; qi < 2; ++qi){
    float l = lsum[qi];
    l += __shfl_xor(l, 16, 64);
    l += __shfl_xor(l, 32, 64);
    float inv = 1.f / l;
    int qw = (qh*16 + wid*2 + qi)*16 + lq;
    if(qw < kS){
      short* op = o + ((size_t)(b*kS + qw))*256 + h*32;
      uint2 w0, w1;
      w0.x = cvtpk(oa0[qi][0]*inv, oa0[qi][1]*inv); w0.y = cvtpk(oa0[qi][2]*inv, oa0[qi][3]*inv);
      w1.x = cvtpk(oa1[qi][0]*inv, oa1[qi][1]*inv); w1.y = cvtpk(oa1[qi][2]*inv, oa1[qi][3]*inv);
      *(uint2*)&op[lg*4] = w0;
      *(uint2*)&op[16 + lg*4] = w1;
    }
  }
}

// ---------------- attention pooling + LN + head ----------------
__global__ __launch_bounds__(256) void pool_head(const float* __restrict__ x,
    const float* __restrict__ pq, const float* __restrict__ og, const float* __restrict__ ob,
    const float* __restrict__ ohW, const float* __restrict__ ohb, float* __restrict__ out){
  int b = blockIdx.x, t = threadIdx.x;
  __shared__ float lg[500];
  __shared__ float red[256];
  const float* xb = x + (size_t)b * 500 * 256;
  for(int s = t; s < 500; s += 256){
    const float* xr = xb + (size_t)s * 256;
    float d = 0.f;
    for(int c = 0; c < 256; ++c) d += xr[c] * pq[c];
    lg[s] = d * 0.0625f;
  }
  __syncthreads();
  float m = -1e30f;
  for(int s = t; s < 500; s += 256) m = fmaxf(m, lg[s]);
  red[t] = m; __syncthreads();
  for(int s2 = 128; s2 > 0; s2 >>= 1){ if(t < s2) red[t] = fmaxf(red[t], red[t+s2]); __syncthreads(); }
  m = red[0]; __syncthreads();
  float ps = 0.f;
  for(int s = t; s < 500; s += 256){ float e = expf(lg[s] - m); lg[s] = e; ps += e; }
  red[t] = ps; __syncthreads();
  for(int s2 = 128; s2 > 0; s2 >>= 1){ if(t < s2) red[t] += red[t+s2]; __syncthreads(); }
  float inv = 1.f / red[0];
  __syncthreads();
  float acc = 0.f;
  for(int s = 0; s < 500; ++s) acc += lg[s] * xb[(size_t)s*256 + t];
  acc *= inv;
  __syncthreads();
  red[t] = acc; __syncthreads();
  for(int s2 = 128; s2 > 0; s2 >>= 1){ if(t < s2) red[t] += red[t+s2]; __syncthreads(); }
  float mean = red[0] / 256.f; __syncthreads();
  float d = acc - mean;
  red[t] = d*d; __syncthreads();
  for(int s2 = 128; s2 > 0; s2 >>= 1){ if(t < s2) red[t] += red[t+s2]; __syncthreads(); }
  float rstd = 1.f / sqrtf(red[0]/256.f + 1e-5f);
  __syncthreads();
  float val = (d*rstd*og[t] + ob[t]) * ohW[t];
  red[t] = val; __syncthreads();
  for(int s2 = 128; s2 > 0; s2 >>= 1){ if(t < s2) red[t] += red[t+s2]; __syncthreads(); }
  if(t == 0) out[b] = red[0] + ohb[0];
}

extern "C" void kernel_launch(void* const* d_in, const int* in_sizes, int n_in,
                              void* d_out, int out_size, void* d_ws, size_t ws_size,
                              hipStream_t stream){
  const float* mel      = (const float*)d_in[0];
  const int*   events   = (const int*)d_in[1];
  const unsigned char* emask = (const unsigned char*)d_in[2];
  const float* star     = (const float*)d_in[3];
  const float* mel_W    = (const float*)d_in[4];
  const float* mel_b    = (const float*)d_in[5];
  const float* conv1_w  = (const float*)d_in[6];
  const float* conv1_b  = (const float*)d_in[7];
  const float* gn_g     = (const float*)d_in[8];
  const float* gn_b     = (const float*)d_in[9];
  const float* conv2_w  = (const float*)d_in[10];
  const float* conv2_b  = (const float*)d_in[11];
  const float* cn_g     = (const float*)d_in[12];
  const float* cn_b     = (const float*)d_in[13];
  const float* star_tab = (const float*)d_in[14];
  const float* ep_W1    = (const float*)d_in[15];
  const float* ep_b1    = (const float*)d_in[16];
  const float* ep_W2    = (const float*)d_in[17];
  const float* ep_b2    = (const float*)d_in[18];
  const float* tl_Wqkv  = (const float*)d_in[19];
  const float* tl_bqkv  = (const float*)d_in[20];
  const float* tl_Wo    = (const float*)d_in[21];
  const float* tl_bo    = (const float*)d_in[22];
  const float* tl_ln1g  = (const float*)d_in[23];
  const float* tl_ln1b  = (const float*)d_in[24];
  const float* tl_ln2g  = (const float*)d_in[25];
  const float* tl_ln2b  = (const float*)d_in[26];
  const float* tl_W1    = (const float*)d_in[27];
  const float* tl_b1    = (const float*)d_in[28];
  const float* tl_W2    = (const float*)d_in[29];
  const float* tl_b2    = (const float*)d_in[30];
  const float* pool_q   = (const float*)d_in[31];
  const float* on_g     = (const float*)d_in[32];
  const float* on_b     = (const float*)d_in[33];
  const float* oh_W     = (const float*)d_in[34];
  const float* oh_b     = (const float*)d_in[35];
  (void)in_sizes; (void)n_in; (void)out_size; (void)ws_size;

  float* ws  = (float*)d_ws;
  float* X   = ws;                        // fp32 (B,S,256)
  short* XNB = (short*)(ws + 4096000);    // bf16 (B,S,256)
  short* OB  = (short*)(ws + 6144000);    // bf16 attn out (B,S,256)
  short* WB  = (short*)(ws + 8192000);    // bf16 weights
  float* BIG = ws + 10812000;             // scratch
  double* PART = (double*)(ws + 28668000);
  float* STATS = ws + 28671900;

  // WB sub-offsets (shorts)
  short* WBc1 = WB + 0;         // 128x128
  short* WBc2 = WB + 16384;     // 256x896
  short* WBe1 = WB + 245760;    // 256x768
  short* WBe2 = WB + 442368;    // 256x256
  short* WBqk = WB + 507904;    // 6 x 768x256
  short* WBwo = WB + 1687552;   // 6 x 256x256
  short* WBw1 = WB + 2080768;   // 6 x 1024x256
  short* WBw2 = WB + 3653632;   // 6 x 256x1024

  // BIG sub-layouts
  float* XMEL = BIG;                       // (B,16,2000)
  short* A1B  = (short*)(BIG + 1024000);   // (32000,128) bf16
  float* H1   = BIG + 3072000;             // (B,1000,128)
  short* A2B  = (short*)(BIG + 7168000);   // (16000,896) bf16
  float* XPRE = BIG;                       // (B,S,256)
  short* COMBB= (short*)BIG;               // (8192,768) bf16
  short* EHIDB= (short*)(BIG + 3146000);   // (8192,256) bf16
  float* EVO  = BIG + 4195000;             // (8192,256) fp32
  short* QKVB = (short*)BIG;               // (16000,768) bf16
  short* HIDB = (short*)(BIG + 7168000);   // (16000,1024) bf16

  // ---- weight conversion (fused) ----
  conv1w_pad<<<128, 128, 0, stream>>>(conv1_w, WBc1);
  f2b_all<<<20352, 256, 0, stream>>>(conv2_w, ep_W1, ep_W2, tl_Wqkv, tl_Wo, tl_W1, tl_W2, WB);

  // ---- prologue ----
  mel_kernel<<<kB*8, 256, 0, stream>>>(mel, mel_W, mel_b, XMEL);
  im2col1b<<<16000, 256, 0, stream>>>(XMEL, A1B);
  gemm_mfma<0,true><<<dim3(1, 250), 256, 0, stream>>>(A1B, WBc1, conv1_b, H1, 32000, 128, 128);
  gn_part<<<256, 256, 0, stream>>>(H1, PART);
  gn_final<<<1, 256, 0, stream>>>(PART, STATS);
  im2col2b<<<56000, 256, 0, stream>>>(H1, STATS, gn_g, gn_b, A2B);
  gemm_mfma<0,true><<<dim3(2, 125), 256, 0, stream>>>(A2B, WBc2, conv2_b, XPRE, 16000, 256, 896);
  postconv<<<16000, 256, 0, stream>>>(XPRE, cn_g, cn_b, star, star_tab, X);
  // events
  event_feat<<<kB*256, 256, 0, stream>>>(events, COMBB);
  gemm_mfma<2,true><<<dim3(2, 64), 256, 0, stream>>>(COMBB, WBe1, ep_b1, EHIDB, 8192, 256, 768);
  gemm_mfma<0,false><<<dim3(2, 64), 256, 0, stream>>>(EHIDB, WBe2, ep_b2, EVO, 8192, 256, 256);
  ev_scatter<<<kB*256, 256, 0, stream>>>(EVO, events, emask, X);

  // ---- transformer layers ----
  ln_rows<<<16000, 256, 0, stream>>>(X, tl_ln1g, tl_ln1b, XNB);   // ln1[0]
  for(int i = 0; i < 6; ++i){
    gemm512<false><<<dim3(3, 125), 512, 0, stream>>>(XNB, WBqk + (size_t)i*196608, tl_bqkv + i*768, QKVB, 16000, 768, 256);
    attn_mfma<<<512, 512, 0, stream>>>(QKVB, OB);
    gemm_ln<true><<<dim3(1, 250), 512, 0, stream>>>(OB, WBwo + (size_t)i*65536, tl_bo + i*256,
        X, tl_ln2g + i*256, tl_ln2b + i*256, XNB, 16000, 256);
    gemm512<true><<<dim3(4, 125), 512, 0, stream>>>(XNB, WBw1 + (size_t)i*262144, tl_b1 + i*1024, HIDB, 16000, 1024, 256);
    if(i < 5)
      gemm_ln<true><<<dim3(1, 250), 512, 0, stream>>>(HIDB, WBw2 + (size_t)i*262144, tl_b2 + i*256,
          X, tl_ln1g + (i+1)*256, tl_ln1b + (i+1)*256, XNB, 16000, 1024);
    else
      gemm_ln<false><<<dim3(1, 250), 512, 0, stream>>>(HIDB, WBw2 + (size_t)i*262144, tl_b2 + i*256,
          X, tl_ln1g, tl_ln1b, XNB, 16000, 1024);
  }

  // ---- pooling + head ----
  pool_head<<<kB, 256, 0, stream>>>(X, pool_q, on_g, on_b, oh_W, oh_b, (float*)d_out);
}